// Round 1
// baseline (8585.364 us; speedup 1.0000x reference)
//
#include <hip/hip_runtime.h>

#define HID 256
#define IN_CH 512

// ---------------- degree / norm ----------------

__global__ __launch_bounds__(256) void k_deg_init(float* __restrict__ deg, int n) {
    int i = blockIdx.x * 256 + threadIdx.x;
    if (i < n) deg[i] = 1.0f;  // self loop
}

__global__ __launch_bounds__(256) void k_deg_count(const int* __restrict__ dst,
                                                   float* __restrict__ deg, int E) {
    int e = blockIdx.x * 256 + threadIdx.x;
    if (e < E) atomicAdd(&deg[dst[e]], 1.0f);
}

__global__ __launch_bounds__(256) void k_dinv(float* __restrict__ deg, int n) {
    int i = blockIdx.x * 256 + threadIdx.x;
    if (i < n) deg[i] = rsqrtf(deg[i]);  // deg >= 1 always
}

// ---------------- fp32 tiled GEMM: C[M,256] = act(A)[M,K] @ B[K,256] ----------------
// 64x64 tile, 256 threads, each thread 4x4 outputs. K staged in 32-chunks via LDS.

template<bool RELU>
__global__ __launch_bounds__(256) void k_gemm(const float* __restrict__ A,
                                              const float* __restrict__ B,
                                              float* __restrict__ C,
                                              int M, int K) {
    __shared__ float As[64][36];  // [m][k], padded stride 36 (16B-aligned rows)
    __shared__ float Bs[32][64];  // [k][n]

    const int m0 = blockIdx.x * 64;
    const int n0 = blockIdx.y * 64;
    const int tid = threadIdx.x;
    const int ty = tid / 16;       // 0..15 -> output rows ty*4..ty*4+3
    const int tx = tid % 16;       // 0..15 -> output cols tx*4..tx*4+3

    float acc[4][4] = {};

    for (int k0 = 0; k0 < K; k0 += 32) {
        // --- load A tile: 64 rows x 32 k; thread t: row=t/4, kc=(t%4)*8 (two float4)
        {
            int row = tid >> 2;
            int kc  = (tid & 3) * 8;
            int gm  = m0 + row;
            float4 v0 = make_float4(0, 0, 0, 0), v1 = v0;
            if (gm < M) {
                const float* ap = A + (size_t)gm * K + k0 + kc;
                v0 = *(const float4*)(ap);
                v1 = *(const float4*)(ap + 4);
            }
            if (RELU) {
                v0.x = fmaxf(v0.x, 0.f); v0.y = fmaxf(v0.y, 0.f);
                v0.z = fmaxf(v0.z, 0.f); v0.w = fmaxf(v0.w, 0.f);
                v1.x = fmaxf(v1.x, 0.f); v1.y = fmaxf(v1.y, 0.f);
                v1.z = fmaxf(v1.z, 0.f); v1.w = fmaxf(v1.w, 0.f);
            }
            *(float4*)&As[row][kc]     = v0;
            *(float4*)&As[row][kc + 4] = v1;
        }
        // --- load B tile: 32 k x 64 n; thread t: k=t/8, n=(t%8)*8 (two float4)
        {
            int k = tid >> 3;
            int nn = (tid & 7) * 8;
            const float* bp = B + (size_t)(k0 + k) * HID + n0 + nn;
            float4 w0 = *(const float4*)(bp);
            float4 w1 = *(const float4*)(bp + 4);
            *(float4*)&Bs[k][nn]     = w0;
            *(float4*)&Bs[k][nn + 4] = w1;
        }
        __syncthreads();

#pragma unroll
        for (int k = 0; k < 32; ++k) {
            float a0 = As[ty * 4 + 0][k];
            float a1 = As[ty * 4 + 1][k];
            float a2 = As[ty * 4 + 2][k];
            float a3 = As[ty * 4 + 3][k];
            float4 b = *(const float4*)&Bs[k][tx * 4];
            acc[0][0] += a0 * b.x; acc[0][1] += a0 * b.y; acc[0][2] += a0 * b.z; acc[0][3] += a0 * b.w;
            acc[1][0] += a1 * b.x; acc[1][1] += a1 * b.y; acc[1][2] += a1 * b.z; acc[1][3] += a1 * b.w;
            acc[2][0] += a2 * b.x; acc[2][1] += a2 * b.y; acc[2][2] += a2 * b.z; acc[2][3] += a2 * b.w;
            acc[3][0] += a3 * b.x; acc[3][1] += a3 * b.y; acc[3][2] += a3 * b.z; acc[3][3] += a3 * b.w;
        }
        __syncthreads();
    }

    // --- epilogue
#pragma unroll
    for (int i = 0; i < 4; ++i) {
        int gm = m0 + ty * 4 + i;
        if (gm < M) {
            float4 r = make_float4(acc[i][0], acc[i][1], acc[i][2], acc[i][3]);
            *(float4*)(C + (size_t)gm * HID + n0 + tx * 4) = r;
        }
    }
}

// ---------------- agg init: agg = bias + h * dinv^2 (self-loop term) ----------------

__global__ __launch_bounds__(256) void k_init_agg(const float* __restrict__ h,
                                                  const float* __restrict__ dinv,
                                                  const float* __restrict__ bias,
                                                  float* __restrict__ agg, int n) {
    int total = n * (HID / 4);
    for (int idx = blockIdx.x * 256 + threadIdx.x; idx < total; idx += gridDim.x * 256) {
        int node = idx >> 6;
        int c4 = (idx & 63) * 4;
        float di = dinv[node];
        float w = di * di;
        float4 v = *(const float4*)(h + (size_t)node * HID + c4);
        float4 b = *(const float4*)(bias + c4);
        float4 r = make_float4(b.x + v.x * w, b.y + v.y * w, b.z + v.z * w, b.w + v.w * w);
        *(float4*)(agg + (size_t)node * HID + c4) = r;
    }
}

// ---------------- edge scatter: agg[dst] += h[src] * dinv[src]*dinv[dst] ----------------
// one wave per edge; each lane handles 4 channels.

__global__ __launch_bounds__(256) void k_scatter(const float* __restrict__ h,
                                                 const float* __restrict__ dinv,
                                                 const int* __restrict__ src,
                                                 const int* __restrict__ dst,
                                                 float* __restrict__ agg, int E) {
    int e = blockIdx.x * 4 + (threadIdx.x >> 6);
    if (e >= E) return;
    int lane = threadIdx.x & 63;
    int s = src[e];
    int d = dst[e];
    float w = dinv[s] * dinv[d];
    float4 v = *(const float4*)(h + (size_t)s * HID + lane * 4);
    float* ap = agg + (size_t)d * HID + lane * 4;
    atomicAdd(ap + 0, v.x * w);
    atomicAdd(ap + 1, v.y * w);
    atomicAdd(ap + 2, v.z * w);
    atomicAdd(ap + 3, v.w * w);
}

// ---------------- readout: out[n] = bout + sum_c relu(h[n][c]) * Wout[c] ----------------

__global__ __launch_bounds__(256) void k_readout(const float* __restrict__ h,
                                                 const float* __restrict__ wout,
                                                 const float* __restrict__ bout,
                                                 float* __restrict__ out, int n) {
    int node = blockIdx.x * 4 + (threadIdx.x >> 6);
    if (node >= n) return;
    int lane = threadIdx.x & 63;
    float4 v = *(const float4*)(h + (size_t)node * HID + lane * 4);
    float4 w = *(const float4*)(wout + lane * 4);
    v.x = fmaxf(v.x, 0.f); v.y = fmaxf(v.y, 0.f);
    v.z = fmaxf(v.z, 0.f); v.w = fmaxf(v.w, 0.f);
    float s = v.x * w.x + v.y * w.y + v.z * w.z + v.w * w.w;
#pragma unroll
    for (int off = 32; off > 0; off >>= 1) s += __shfl_down(s, off, 64);
    if (lane == 0) out[node] = s + bout[0];
}

// ---------------- launch ----------------

extern "C" void kernel_launch(void* const* d_in, const int* in_sizes, int n_in,
                              void* d_out, int out_size, void* d_ws, size_t ws_size,
                              hipStream_t stream) {
    const float* x    = (const float*)d_in[0];
    const int*   ei   = (const int*)d_in[1];
    const float* W0   = (const float*)d_in[2];
    const float* b0   = (const float*)d_in[3];
    const float* W1   = (const float*)d_in[4];
    const float* b1   = (const float*)d_in[5];
    const float* W2   = (const float*)d_in[6];
    const float* b2   = (const float*)d_in[7];
    const float* Wout = (const float*)d_in[8];
    const float* bout = (const float*)d_in[9];
    float* out = (float*)d_out;

    const int n = in_sizes[0] / IN_CH;   // 50000
    const int E = in_sizes[1] / 2;       // 800000
    const int* src = ei;
    const int* dst = ei + E;

    // workspace carve-up
    float* deg  = (float*)d_ws;                       // n (padded to 50176)
    float* bufA = deg + 50176;                        // n*256
    float* bufB = bufA + (size_t)n * HID;             // n*256

    const int nb_n = (n + 255) / 256;
    const int nb_e = (E + 255) / 256;

    // norm
    k_deg_init<<<nb_n, 256, 0, stream>>>(deg, n);
    k_deg_count<<<nb_e, 256, 0, stream>>>(dst, deg, E);
    k_dinv<<<nb_n, 256, 0, stream>>>(deg, n);

    dim3 gg((n + 63) / 64, HID / 64);
    const int scat_blocks = (E + 3) / 4;
    const int ro_blocks = (n + 3) / 4;

    // layer 0: h = x @ W0
    k_gemm<false><<<gg, 256, 0, stream>>>(x, W0, bufA, n, IN_CH);
    k_init_agg<<<2048, 256, 0, stream>>>(bufA, deg, b0, bufB, n);
    k_scatter<<<scat_blocks, 256, 0, stream>>>(bufA, deg, src, dst, bufB, E);

    // layer 1: h = relu(agg0) @ W1
    k_gemm<true><<<gg, 256, 0, stream>>>(bufB, W1, bufA, n, HID);
    k_init_agg<<<2048, 256, 0, stream>>>(bufA, deg, b1, bufB, n);
    k_scatter<<<scat_blocks, 256, 0, stream>>>(bufA, deg, src, dst, bufB, E);

    // layer 2: h = relu(agg1) @ W2
    k_gemm<true><<<gg, 256, 0, stream>>>(bufB, W2, bufA, n, HID);
    k_init_agg<<<2048, 256, 0, stream>>>(bufA, deg, b2, bufB, n);
    k_scatter<<<scat_blocks, 256, 0, stream>>>(bufA, deg, src, dst, bufB, E);

    // readout
    k_readout<<<ro_blocks, 256, 0, stream>>>(bufB, Wout, bout, out, n);
}

// Round 2
// 971.767 us; speedup vs baseline: 8.8348x; 8.8348x over previous
//
#include <hip/hip_runtime.h>

#define HID 256
#define IN_CH 512
#define NPAD 50176   // n rounded up, for ws carving

// ---------------- CSR build ----------------

__global__ __launch_bounds__(256) void k_count(const int* __restrict__ dst,
                                               int* __restrict__ cnt, int E) {
    int e = blockIdx.x * 256 + threadIdx.x;
    if (e < E) atomicAdd(&cnt[dst[e]], 1);
}

// pass 1: block sums (1024 elems / block)
__global__ __launch_bounds__(256) void k_scan_bsum(const int* __restrict__ cnt,
                                                   int* __restrict__ bsum, int n) {
    __shared__ int sdata[256];
    int t = threadIdx.x;
    int base = blockIdx.x * 1024 + t * 4;
    int s = 0;
#pragma unroll
    for (int j = 0; j < 4; ++j) if (base + j < n) s += cnt[base + j];
    sdata[t] = s;
    __syncthreads();
    for (int off = 128; off > 0; off >>= 1) {
        if (t < off) sdata[t] += sdata[t + off];
        __syncthreads();
    }
    if (t == 0) bsum[blockIdx.x] = sdata[0];
}

// pass 2: exclusive scan of <=64 block sums, single wave
__global__ __launch_bounds__(64) void k_scan_boff(const int* __restrict__ bsum,
                                                  int* __restrict__ boff, int nb) {
    int lane = threadIdx.x;
    int own = (lane < nb) ? bsum[lane] : 0;
    int v = own;
    for (int off = 1; off < 64; off <<= 1) {
        int u = __shfl_up(v, off, 64);
        if (lane >= off) v += u;
    }
    if (lane < nb) boff[lane] = v - own;  // exclusive
}

// pass 3: write rowptr[i+1] = global inclusive prefix
__global__ __launch_bounds__(256) void k_scan_write(const int* __restrict__ cnt,
                                                    const int* __restrict__ boff,
                                                    int* __restrict__ rowptr, int n) {
    __shared__ int sdata[256];
    int t = threadIdx.x;
    int base = blockIdx.x * 1024 + t * 4;
    int c0 = (base + 0 < n) ? cnt[base + 0] : 0;
    int c1 = (base + 1 < n) ? cnt[base + 1] : 0;
    int c2 = (base + 2 < n) ? cnt[base + 2] : 0;
    int c3 = (base + 3 < n) ? cnt[base + 3] : 0;
    int tsum = c0 + c1 + c2 + c3;
    sdata[t] = tsum;
    __syncthreads();
    for (int off = 1; off < 256; off <<= 1) {
        int v = (t >= off) ? sdata[t - off] : 0;
        __syncthreads();
        if (t >= off) sdata[t] += v;
        __syncthreads();
    }
    int excl = sdata[t] - tsum;
    int p = boff[blockIdx.x] + excl;
    if (base + 0 < n) rowptr[base + 1] = p + c0;
    if (base + 1 < n) rowptr[base + 2] = p + c0 + c1;
    if (base + 2 < n) rowptr[base + 3] = p + c0 + c1 + c2;
    if (base + 3 < n) rowptr[base + 4] = p + c0 + c1 + c2 + c3;
    if (blockIdx.x == 0 && t == 0) rowptr[0] = 0;
}

__global__ __launch_bounds__(256) void k_dinv(const int* __restrict__ cnt,
                                              float* __restrict__ dinv, int n) {
    int i = blockIdx.x * 256 + threadIdx.x;
    if (i < n) dinv[i] = rsqrtf((float)(cnt[i] + 1));  // +1 self loop
}

__global__ __launch_bounds__(256) void k_fill(const int* __restrict__ src,
                                              const int* __restrict__ dst,
                                              const int* __restrict__ rowptr,
                                              int* __restrict__ cursor,
                                              int* __restrict__ ssrc, int E) {
    int e = blockIdx.x * 256 + threadIdx.x;
    if (e >= E) return;
    int d = dst[e];
    int pos = rowptr[d] + atomicAdd(&cursor[d], 1);
    ssrc[pos] = src[e];
}

// ---------------- fp32 tiled GEMM: C[M,256] = act(A)[M,K] @ B[K,256] ----------------

template<bool RELU>
__global__ __launch_bounds__(256) void k_gemm(const float* __restrict__ A,
                                              const float* __restrict__ B,
                                              float* __restrict__ C,
                                              int M, int K) {
    __shared__ float As[64][36];
    __shared__ float Bs[32][64];

    const int m0 = blockIdx.x * 64;
    const int n0 = blockIdx.y * 64;
    const int tid = threadIdx.x;
    const int ty = tid / 16;
    const int tx = tid % 16;

    float acc[4][4] = {};

    for (int k0 = 0; k0 < K; k0 += 32) {
        {
            int row = tid >> 2;
            int kc  = (tid & 3) * 8;
            int gm  = m0 + row;
            float4 v0 = make_float4(0, 0, 0, 0), v1 = v0;
            if (gm < M) {
                const float* ap = A + (size_t)gm * K + k0 + kc;
                v0 = *(const float4*)(ap);
                v1 = *(const float4*)(ap + 4);
            }
            if (RELU) {
                v0.x = fmaxf(v0.x, 0.f); v0.y = fmaxf(v0.y, 0.f);
                v0.z = fmaxf(v0.z, 0.f); v0.w = fmaxf(v0.w, 0.f);
                v1.x = fmaxf(v1.x, 0.f); v1.y = fmaxf(v1.y, 0.f);
                v1.z = fmaxf(v1.z, 0.f); v1.w = fmaxf(v1.w, 0.f);
            }
            *(float4*)&As[row][kc]     = v0;
            *(float4*)&As[row][kc + 4] = v1;
        }
        {
            int k = tid >> 3;
            int nn = (tid & 7) * 8;
            const float* bp = B + (size_t)(k0 + k) * HID + n0 + nn;
            float4 w0 = *(const float4*)(bp);
            float4 w1 = *(const float4*)(bp + 4);
            *(float4*)&Bs[k][nn]     = w0;
            *(float4*)&Bs[k][nn + 4] = w1;
        }
        __syncthreads();

#pragma unroll
        for (int k = 0; k < 32; ++k) {
            float a0 = As[ty * 4 + 0][k];
            float a1 = As[ty * 4 + 1][k];
            float a2 = As[ty * 4 + 2][k];
            float a3 = As[ty * 4 + 3][k];
            float4 b = *(const float4*)&Bs[k][tx * 4];
            acc[0][0] += a0 * b.x; acc[0][1] += a0 * b.y; acc[0][2] += a0 * b.z; acc[0][3] += a0 * b.w;
            acc[1][0] += a1 * b.x; acc[1][1] += a1 * b.y; acc[1][2] += a1 * b.z; acc[1][3] += a1 * b.w;
            acc[2][0] += a2 * b.x; acc[2][1] += a2 * b.y; acc[2][2] += a2 * b.z; acc[2][3] += a2 * b.w;
            acc[3][0] += a3 * b.x; acc[3][1] += a3 * b.y; acc[3][2] += a3 * b.z; acc[3][3] += a3 * b.w;
        }
        __syncthreads();
    }

#pragma unroll
    for (int i = 0; i < 4; ++i) {
        int gm = m0 + ty * 4 + i;
        if (gm < M) {
            float4 r = make_float4(acc[i][0], acc[i][1], acc[i][2], acc[i][3]);
            *(float4*)(C + (size_t)gm * HID + n0 + tx * 4) = r;
        }
    }
}

// ---------------- gather aggregate: one wave per dst node ----------------
// agg[d] = bias + h[d]*dinv[d]^2 + sum_{s in row(d)} h[s]*dinv[s]*dinv[d]
// If READOUT: instead emit out[d] = bout + dot(relu(agg_row), wout)

template<bool READOUT>
__global__ __launch_bounds__(256) void k_aggregate(const float* __restrict__ h,
                                                   const float* __restrict__ dinv,
                                                   const int* __restrict__ rowptr,
                                                   const int* __restrict__ ssrc,
                                                   const float* __restrict__ bias,
                                                   float* __restrict__ agg,
                                                   const float* __restrict__ wout,
                                                   const float* __restrict__ bout,
                                                   float* __restrict__ out,
                                                   int n) {
    int node = blockIdx.x * 4 + (threadIdx.x >> 6);
    if (node >= n) return;
    int lane = threadIdx.x & 63;

    float dd = dinv[node];
    float4 acc;
    {
        float w = dd * dd;
        float4 v = *(const float4*)(h + (size_t)node * HID + lane * 4);
        float4 b = *(const float4*)(bias + lane * 4);
        acc = make_float4(b.x + v.x * w, b.y + v.y * w, b.z + v.z * w, b.w + v.w * w);
    }

    int e = rowptr[node];
    int e_end = rowptr[node + 1];
    for (; e + 1 < e_end; e += 2) {
        int s0 = ssrc[e], s1 = ssrc[e + 1];
        float w0 = dinv[s0] * dd;
        float w1 = dinv[s1] * dd;
        float4 v0 = *(const float4*)(h + (size_t)s0 * HID + lane * 4);
        float4 v1 = *(const float4*)(h + (size_t)s1 * HID + lane * 4);
        acc.x += v0.x * w0 + v1.x * w1;
        acc.y += v0.y * w0 + v1.y * w1;
        acc.z += v0.z * w0 + v1.z * w1;
        acc.w += v0.w * w0 + v1.w * w1;
    }
    if (e < e_end) {
        int s0 = ssrc[e];
        float w0 = dinv[s0] * dd;
        float4 v0 = *(const float4*)(h + (size_t)s0 * HID + lane * 4);
        acc.x += v0.x * w0; acc.y += v0.y * w0;
        acc.z += v0.z * w0; acc.w += v0.w * w0;
    }

    if (!READOUT) {
        *(float4*)(agg + (size_t)node * HID + lane * 4) = acc;
    } else {
        float4 w = *(const float4*)(wout + lane * 4);
        acc.x = fmaxf(acc.x, 0.f); acc.y = fmaxf(acc.y, 0.f);
        acc.z = fmaxf(acc.z, 0.f); acc.w = fmaxf(acc.w, 0.f);
        float s = acc.x * w.x + acc.y * w.y + acc.z * w.z + acc.w * w.w;
#pragma unroll
        for (int off = 32; off > 0; off >>= 1) s += __shfl_down(s, off, 64);
        if (lane == 0) out[node] = s + bout[0];
    }
}

// ---------------- launch ----------------

extern "C" void kernel_launch(void* const* d_in, const int* in_sizes, int n_in,
                              void* d_out, int out_size, void* d_ws, size_t ws_size,
                              hipStream_t stream) {
    const float* x    = (const float*)d_in[0];
    const int*   ei   = (const int*)d_in[1];
    const float* W0   = (const float*)d_in[2];
    const float* b0   = (const float*)d_in[3];
    const float* W1   = (const float*)d_in[4];
    const float* b1   = (const float*)d_in[5];
    const float* W2   = (const float*)d_in[6];
    const float* b2   = (const float*)d_in[7];
    const float* Wout = (const float*)d_in[8];
    const float* bout = (const float*)d_in[9];
    float* out = (float*)d_out;

    const int n = in_sizes[0] / IN_CH;   // 50000
    const int E = in_sizes[1] / 2;       // 800000
    const int* src = ei;
    const int* dst = ei + E;

    // workspace carve-up (all 16B-aligned chunks)
    float* dinv   = (float*)d_ws;                  // NPAD
    int*   rowptr = (int*)(dinv + NPAD);           // NPAD (need n+1)
    int*   cursor = rowptr + NPAD;                 // NPAD
    int*   ssrc   = cursor + NPAD;                 // E
    int*   bsum   = ssrc + 800000;                 // 64
    int*   boff   = bsum + 64;                     // 64
    float* bufA   = (float*)(boff + 64);           // n*HID
    float* bufB   = bufA + (size_t)n * HID;        // n*HID

    const int nb_n = (n + 255) / 256;
    const int nb_e = (E + 255) / 256;
    const int nb_scan = (n + 1023) / 1024;         // 49

    // ---- CSR build ----
    hipMemsetAsync(cursor, 0, (size_t)n * 4, stream);
    k_count<<<nb_e, 256, 0, stream>>>(dst, cursor, E);
    k_scan_bsum<<<nb_scan, 256, 0, stream>>>(cursor, bsum, n);
    k_scan_boff<<<1, 64, 0, stream>>>(bsum, boff, nb_scan);
    k_scan_write<<<nb_scan, 256, 0, stream>>>(cursor, boff, rowptr, n);
    k_dinv<<<nb_n, 256, 0, stream>>>(cursor, dinv, n);
    hipMemsetAsync(cursor, 0, (size_t)n * 4, stream);
    k_fill<<<nb_e, 256, 0, stream>>>(src, dst, rowptr, cursor, ssrc, E);

    dim3 gg((n + 63) / 64, HID / 64);
    const int agg_blocks = (n + 3) / 4;

    // layer 0
    k_gemm<false><<<gg, 256, 0, stream>>>(x, W0, bufA, n, IN_CH);
    k_aggregate<false><<<agg_blocks, 256, 0, stream>>>(bufA, dinv, rowptr, ssrc, b0,
                                                       bufB, nullptr, nullptr, nullptr, n);
    // layer 1
    k_gemm<true><<<gg, 256, 0, stream>>>(bufB, W1, bufA, n, HID);
    k_aggregate<false><<<agg_blocks, 256, 0, stream>>>(bufA, dinv, rowptr, ssrc, b1,
                                                       bufB, nullptr, nullptr, nullptr, n);
    // layer 2 + fused readout
    k_gemm<true><<<gg, 256, 0, stream>>>(bufB, W2, bufA, n, HID);
    k_aggregate<true><<<agg_blocks, 256, 0, stream>>>(bufA, dinv, rowptr, ssrc, b2,
                                                      nullptr, Wout, bout, out, n);
}

// Round 3
// 722.086 us; speedup vs baseline: 11.8897x; 1.3458x over previous
//
#include <hip/hip_runtime.h>

#define HID 256
#define IN_CH 512
#define NPAD 50176

typedef __attribute__((ext_vector_type(8))) short s16x8;
typedef __attribute__((ext_vector_type(4))) float f32x4;

#define GLBP(p) ((const __attribute__((address_space(1))) void*)(p))
#define LDSP(p) ((__attribute__((address_space(3))) void*)(p))

// ---------------- CSR build ----------------

__global__ __launch_bounds__(256) void k_count(const int* __restrict__ dst,
                                               int* __restrict__ cnt, int E) {
    int e = blockIdx.x * 256 + threadIdx.x;
    if (e < E) atomicAdd(&cnt[dst[e]], 1);
}

__global__ __launch_bounds__(256) void k_scan_bsum(const int* __restrict__ cnt,
                                                   int* __restrict__ bsum, int n) {
    __shared__ int sdata[256];
    int t = threadIdx.x;
    int base = blockIdx.x * 1024 + t * 4;
    int s = 0;
#pragma unroll
    for (int j = 0; j < 4; ++j) if (base + j < n) s += cnt[base + j];
    sdata[t] = s;
    __syncthreads();
    for (int off = 128; off > 0; off >>= 1) {
        if (t < off) sdata[t] += sdata[t + off];
        __syncthreads();
    }
    if (t == 0) bsum[blockIdx.x] = sdata[0];
}

__global__ __launch_bounds__(64) void k_scan_boff(const int* __restrict__ bsum,
                                                  int* __restrict__ boff, int nb) {
    int lane = threadIdx.x;
    int own = (lane < nb) ? bsum[lane] : 0;
    int v = own;
    for (int off = 1; off < 64; off <<= 1) {
        int u = __shfl_up(v, off, 64);
        if (lane >= off) v += u;
    }
    if (lane < nb) boff[lane] = v - own;
}

__global__ __launch_bounds__(256) void k_scan_write(const int* __restrict__ cnt,
                                                    const int* __restrict__ boff,
                                                    int* __restrict__ rowptr, int n) {
    __shared__ int sdata[256];
    int t = threadIdx.x;
    int base = blockIdx.x * 1024 + t * 4;
    int c0 = (base + 0 < n) ? cnt[base + 0] : 0;
    int c1 = (base + 1 < n) ? cnt[base + 1] : 0;
    int c2 = (base + 2 < n) ? cnt[base + 2] : 0;
    int c3 = (base + 3 < n) ? cnt[base + 3] : 0;
    int tsum = c0 + c1 + c2 + c3;
    sdata[t] = tsum;
    __syncthreads();
    for (int off = 1; off < 256; off <<= 1) {
        int v = (t >= off) ? sdata[t - off] : 0;
        __syncthreads();
        if (t >= off) sdata[t] += v;
        __syncthreads();
    }
    int excl = sdata[t] - tsum;
    int p = boff[blockIdx.x] + excl;
    if (base + 0 < n) rowptr[base + 1] = p + c0;
    if (base + 1 < n) rowptr[base + 2] = p + c0 + c1;
    if (base + 2 < n) rowptr[base + 3] = p + c0 + c1 + c2;
    if (base + 3 < n) rowptr[base + 4] = p + c0 + c1 + c2 + c3;
    if (blockIdx.x == 0 && t == 0) rowptr[0] = 0;
}

__global__ __launch_bounds__(256) void k_dinv(const int* __restrict__ cnt,
                                              float* __restrict__ dinv, int n) {
    int i = blockIdx.x * 256 + threadIdx.x;
    if (i < n) dinv[i] = rsqrtf((float)(cnt[i] + 1));
}

__global__ __launch_bounds__(256) void k_fill(const int* __restrict__ src,
                                              const int* __restrict__ dst,
                                              const int* __restrict__ rowptr,
                                              int* __restrict__ cursor,
                                              int* __restrict__ ssrc, int E) {
    int e = blockIdx.x * 256 + threadIdx.x;
    if (e >= E) return;
    int d = dst[e];
    int pos = rowptr[d] + atomicAdd(&cursor[d], 1);
    ssrc[pos] = src[e];
}

// ---------------- weight pre-split: W[K][256] fp32 -> Bt'[K/32][256][104] bf16 ----------------
// eff col 3j+0 = hi(b), 3j+1 = hi(b), 3j+2 = lo(b); cols 96..103 are pad (never read by MFMA).

__global__ __launch_bounds__(256) void k_wsplit(const float* __restrict__ W,
                                                unsigned short* __restrict__ Bt,
                                                int K) {
    int t = blockIdx.x * 256 + threadIdx.x;
    if (t >= K * HID) return;
    int n = t & 255;
    int k = t >> 8;
    float w = W[(size_t)k * HID + n];
    unsigned int u = __float_as_uint(w);
    unsigned short hi = (unsigned short)(u >> 16);
    float hif = __uint_as_float(u & 0xffff0000u);
    float lo = w - hif;
    unsigned short lob = (unsigned short)(__float_as_uint(lo) >> 16);
    unsigned short* p = Bt + (size_t)(k >> 5) * (HID * 104) + n * 104 + 3 * (k & 31);
    p[0] = hi; p[1] = hi; p[2] = lob;
}

// ---------------- MFMA GEMM: C[M,256] = act(A)[M,K] @ W[K,256] via split-bf16 ----------------
// BM=128, BN=256 (full), BK_orig=32 (BK_eff=96). 512 threads = 8 waves (2m x 4n),
// wave tile 64x64 -> 4x4 fragments of 16x16x32.
// A' eff triplet per orig col: {hi, lo, hi}; B' (pre-split): {hi, hi, lo}.

template<bool RELU>
__global__ __launch_bounds__(512) void k_gemm_mfma(const float* __restrict__ A,
                                                   const unsigned short* __restrict__ Bt,
                                                   float* __restrict__ C,
                                                   int M, int Korig) {
    __shared__ unsigned short Als[128 * 104];  // 26,624 B, row stride 208 B
    __shared__ unsigned short Bls[256 * 104];  // 53,248 B, row stride 208 B (Bt layout: [n][k_eff])

    const int m0 = blockIdx.x * 128;
    const int tid = threadIdx.x;
    const int wave = tid >> 6;
    const int lane = tid & 63;
    const int wm = wave >> 2;      // 0..1
    const int wn = wave & 3;       // 0..3

    f32x4 acc[4][4] = {};          // [m-frag][n-frag]

    const int nsteps = Korig >> 5;
    const int arow = tid >> 2;           // 0..127
    const int aseg = (tid & 3) * 8;      // orig col offset within 32

    for (int ks = 0; ks < nsteps; ++ks) {
        // ---- stage A: load 8 fp32, split, interleave, 3x ds_write_b128 ----
        {
            int gm = m0 + arow;
            float4 v0 = make_float4(0, 0, 0, 0), v1 = v0;
            if (gm < M) {
                const float* ap = A + (size_t)gm * Korig + ks * 32 + aseg;
                v0 = *(const float4*)ap;
                v1 = *(const float4*)(ap + 4);
            }
            float av[8] = {v0.x, v0.y, v0.z, v0.w, v1.x, v1.y, v1.z, v1.w};
            unsigned short hi[8], lo[8];
#pragma unroll
            for (int j = 0; j < 8; ++j) {
                float a = av[j];
                if (RELU) a = fmaxf(a, 0.f);
                unsigned int u = __float_as_uint(a);
                hi[j] = (unsigned short)(u >> 16);
                float hif = __uint_as_float(u & 0xffff0000u);
                float l = a - hif;
                lo[j] = (unsigned short)(__float_as_uint(l) >> 16);
            }
            s16x8 w0 = {(short)hi[0], (short)lo[0], (short)hi[0], (short)hi[1],
                        (short)lo[1], (short)hi[1], (short)hi[2], (short)lo[2]};
            s16x8 w1 = {(short)hi[2], (short)hi[3], (short)lo[3], (short)hi[3],
                        (short)hi[4], (short)lo[4], (short)hi[4], (short)hi[5]};
            s16x8 w2 = {(short)lo[5], (short)hi[5], (short)hi[6], (short)lo[6],
                        (short)hi[6], (short)hi[7], (short)lo[7], (short)hi[7]};
            s16x8* dp = (s16x8*)&Als[arow * 104 + (tid & 3) * 24];
            dp[0] = w0; dp[1] = w1; dp[2] = w2;
        }
        // ---- stage B': 53,248 B = 3328 x 16B chunks = 52 wave-groups, global_load_lds ----
        {
            const char* src = (const char*)(Bt + (size_t)ks * (HID * 104));
            for (int g = wave; g < 52; g += 8) {
                int byteoff = (g * 64 + lane) * 16;
                __builtin_amdgcn_global_load_lds(GLBP(src + byteoff),
                                                 LDSP((char*)Bls + byteoff), 16, 0, 0);
            }
        }
        __syncthreads();

        // ---- MFMA: 3 eff-k steps of 32 ----
#pragma unroll
        for (int kk = 0; kk < 3; ++kk) {
            int gsh = (kk * 4 + (lane >> 4)) * 8;   // granule offset in shorts
            s16x8 af[4], bf[4];
#pragma unroll
            for (int mf = 0; mf < 4; ++mf) {
                int row = wm * 64 + mf * 16 + (lane & 15);
                af[mf] = *(const s16x8*)&Als[row * 104 + gsh];
            }
#pragma unroll
            for (int nf = 0; nf < 4; ++nf) {
                int col = wn * 64 + nf * 16 + (lane & 15);
                bf[nf] = *(const s16x8*)&Bls[col * 104 + gsh];
            }
#pragma unroll
            for (int mf = 0; mf < 4; ++mf)
#pragma unroll
                for (int nf = 0; nf < 4; ++nf)
                    acc[mf][nf] = __builtin_amdgcn_mfma_f32_16x16x32_bf16(af[mf], bf[nf],
                                                                          acc[mf][nf], 0, 0, 0);
        }
        __syncthreads();
    }

    // ---- epilogue: C/D layout col=lane&15, row=(lane>>4)*4+r ----
#pragma unroll
    for (int mf = 0; mf < 4; ++mf) {
        int row0 = m0 + wm * 64 + mf * 16 + (lane >> 4) * 4;
#pragma unroll
        for (int r = 0; r < 4; ++r) {
            int gr = row0 + r;
            if (gr < M) {
#pragma unroll
                for (int nf = 0; nf < 4; ++nf) {
                    int col = wn * 64 + nf * 16 + (lane & 15);
                    C[(size_t)gr * HID + col] = acc[mf][nf][r];
                }
            }
        }
    }
}

// ---------------- gather aggregate (unchanged from round 2) ----------------

template<bool READOUT>
__global__ __launch_bounds__(256) void k_aggregate(const float* __restrict__ h,
                                                   const float* __restrict__ dinv,
                                                   const int* __restrict__ rowptr,
                                                   const int* __restrict__ ssrc,
                                                   const float* __restrict__ bias,
                                                   float* __restrict__ agg,
                                                   const float* __restrict__ wout,
                                                   const float* __restrict__ bout,
                                                   float* __restrict__ out,
                                                   int n) {
    int node = blockIdx.x * 4 + (threadIdx.x >> 6);
    if (node >= n) return;
    int lane = threadIdx.x & 63;

    float dd = dinv[node];
    float4 acc;
    {
        float w = dd * dd;
        float4 v = *(const float4*)(h + (size_t)node * HID + lane * 4);
        float4 b = *(const float4*)(bias + lane * 4);
        acc = make_float4(b.x + v.x * w, b.y + v.y * w, b.z + v.z * w, b.w + v.w * w);
    }

    int e = rowptr[node];
    int e_end = rowptr[node + 1];
    for (; e + 1 < e_end; e += 2) {
        int s0 = ssrc[e], s1 = ssrc[e + 1];
        float w0 = dinv[s0] * dd;
        float w1 = dinv[s1] * dd;
        float4 v0 = *(const float4*)(h + (size_t)s0 * HID + lane * 4);
        float4 v1 = *(const float4*)(h + (size_t)s1 * HID + lane * 4);
        acc.x += v0.x * w0 + v1.x * w1;
        acc.y += v0.y * w0 + v1.y * w1;
        acc.z += v0.z * w0 + v1.z * w1;
        acc.w += v0.w * w0 + v1.w * w1;
    }
    if (e < e_end) {
        int s0 = ssrc[e];
        float w0 = dinv[s0] * dd;
        float4 v0 = *(const float4*)(h + (size_t)s0 * HID + lane * 4);
        acc.x += v0.x * w0; acc.y += v0.y * w0;
        acc.z += v0.z * w0; acc.w += v0.w * w0;
    }

    if (!READOUT) {
        *(float4*)(agg + (size_t)node * HID + lane * 4) = acc;
    } else {
        float4 w = *(const float4*)(wout + lane * 4);
        acc.x = fmaxf(acc.x, 0.f); acc.y = fmaxf(acc.y, 0.f);
        acc.z = fmaxf(acc.z, 0.f); acc.w = fmaxf(acc.w, 0.f);
        float s = acc.x * w.x + acc.y * w.y + acc.z * w.z + acc.w * w.w;
#pragma unroll
        for (int off = 32; off > 0; off >>= 1) s += __shfl_down(s, off, 64);
        if (lane == 0) out[node] = s + bout[0];
    }
}

// ---------------- launch ----------------

extern "C" void kernel_launch(void* const* d_in, const int* in_sizes, int n_in,
                              void* d_out, int out_size, void* d_ws, size_t ws_size,
                              hipStream_t stream) {
    const float* x    = (const float*)d_in[0];
    const int*   ei   = (const int*)d_in[1];
    const float* W0   = (const float*)d_in[2];
    const float* b0   = (const float*)d_in[3];
    const float* W1   = (const float*)d_in[4];
    const float* b1   = (const float*)d_in[5];
    const float* W2   = (const float*)d_in[6];
    const float* b2   = (const float*)d_in[7];
    const float* Wout = (const float*)d_in[8];
    const float* bout = (const float*)d_in[9];
    float* out = (float*)d_out;

    const int n = in_sizes[0] / IN_CH;   // 50000
    const int E = in_sizes[1] / 2;       // 800000
    const int* src = ei;
    const int* dst = ei + E;

    // workspace carve-up
    float* dinv   = (float*)d_ws;                        // NPAD
    int*   rowptr = (int*)(dinv + NPAD);                 // NPAD
    int*   cursor = rowptr + NPAD;                       // NPAD
    int*   ssrc   = cursor + NPAD;                       // E
    int*   bsum   = ssrc + 800000;                       // 64
    int*   boff   = bsum + 64;                           // 64
    unsigned short* Bt0 = (unsigned short*)(boff + 64);  // 16*256*104
    unsigned short* Bt1 = Bt0 + 16 * HID * 104;          // 8*256*104
    unsigned short* Bt2 = Bt1 + 8 * HID * 104;           // 8*256*104
    float* bufA   = (float*)(Bt2 + 8 * HID * 104);       // n*HID
    float* bufB   = bufA + (size_t)n * HID;              // n*HID

    const int nb_n = (n + 255) / 256;
    const int nb_e = (E + 255) / 256;
    const int nb_scan = (n + 1023) / 1024;

    // ---- CSR build ----
    hipMemsetAsync(cursor, 0, (size_t)n * 4, stream);
    k_count<<<nb_e, 256, 0, stream>>>(dst, cursor, E);
    k_scan_bsum<<<nb_scan, 256, 0, stream>>>(cursor, bsum, n);
    k_scan_boff<<<1, 64, 0, stream>>>(bsum, boff, nb_scan);
    k_scan_write<<<nb_scan, 256, 0, stream>>>(cursor, boff, rowptr, n);
    k_dinv<<<nb_n, 256, 0, stream>>>(cursor, dinv, n);
    hipMemsetAsync(cursor, 0, (size_t)n * 4, stream);
    k_fill<<<nb_e, 256, 0, stream>>>(src, dst, rowptr, cursor, ssrc, E);

    // ---- weight pre-split ----
    k_wsplit<<<(IN_CH * HID) / 256, 256, 0, stream>>>(W0, Bt0, IN_CH);
    k_wsplit<<<(HID * HID) / 256, 256, 0, stream>>>(W1, Bt1, HID);
    k_wsplit<<<(HID * HID) / 256, 256, 0, stream>>>(W2, Bt2, HID);

    const int gemm_blocks = (n + 127) / 128;
    const int agg_blocks = (n + 3) / 4;

    // layer 0
    k_gemm_mfma<false><<<gemm_blocks, 512, 0, stream>>>(x, Bt0, bufA, n, IN_CH);
    k_aggregate<false><<<agg_blocks, 256, 0, stream>>>(bufA, dinv, rowptr, ssrc, b0,
                                                       bufB, nullptr, nullptr, nullptr, n);
    // layer 1
    k_gemm_mfma<true><<<gemm_blocks, 512, 0, stream>>>(bufB, Bt1, bufA, n, HID);
    k_aggregate<false><<<agg_blocks, 256, 0, stream>>>(bufA, dinv, rowptr, ssrc, b1,
                                                       bufB, nullptr, nullptr, nullptr, n);
    // layer 2 + fused readout
    k_gemm_mfma<true><<<gemm_blocks, 512, 0, stream>>>(bufB, Bt2, bufA, n, HID);
    k_aggregate<true><<<agg_blocks, 256, 0, stream>>>(bufA, dinv, rowptr, ssrc, b2,
                                                      nullptr, Wout, bout, out, n);
}